// Round 1
// baseline (812.200 us; speedup 1.0000x reference)
//
#include <hip/hip_runtime.h>
#include <hip/hip_bf16.h>

// GCN 2-layer forward: N=50000 nodes, E=1e6 edges, D=256, fp32.
// Pipeline: deg/dinv -> CSR-by-dst build -> [GEMM -> gather(+bias,+relu)] x2.

#define D 256
#define SCAN_B 512

// ---- phase 1: degree + per-dst counts ----
__global__ void pass1_kernel(const int* __restrict__ dst, const float* __restrict__ ew,
                             float* __restrict__ deg, int* __restrict__ counts, int E) {
    int e = blockIdx.x * 256 + threadIdx.x;
    if (e < E) {
        int d = dst[e];
        atomicAdd(&deg[d], ew[e]);
        atomicAdd(&counts[d], 1);
    }
}

__global__ void dinv_kernel(float* __restrict__ deg_dinv, int n) {
    int i = blockIdx.x * 256 + threadIdx.x;
    if (i < n) {
        float d = deg_dinv[i] + 1.0f;   // self-loop weight 1
        deg_dinv[i] = (d > 0.0f) ? rsqrtf(d) : 0.0f;
    }
}

// ---- hierarchical exclusive scan of counts -> row_start ----
__global__ void scan1_kernel(const int* __restrict__ counts, int* __restrict__ row_start,
                             int* __restrict__ blockSums, int n) {
    __shared__ int s[SCAN_B];
    int t = threadIdx.x;
    int gid = blockIdx.x * SCAN_B + t;
    int v = (gid < n) ? counts[gid] : 0;
    s[t] = v;
    __syncthreads();
    for (int off = 1; off < SCAN_B; off <<= 1) {
        int add = (t >= off) ? s[t - off] : 0;
        __syncthreads();
        s[t] += add;
        __syncthreads();
    }
    if (gid < n) row_start[gid] = s[t] - v;  // block-local exclusive
    if (t == SCAN_B - 1) blockSums[blockIdx.x] = s[SCAN_B - 1];
}

__global__ void scan2_kernel(const int* __restrict__ blockSums, int* __restrict__ blockOffsets, int nb) {
    __shared__ int s[128];
    int t = threadIdx.x;
    int v = (t < nb) ? blockSums[t] : 0;
    s[t] = v;
    __syncthreads();
    for (int off = 1; off < 128; off <<= 1) {
        int add = (t >= off) ? s[t - off] : 0;
        __syncthreads();
        s[t] += add;
        __syncthreads();
    }
    if (t < nb) blockOffsets[t] = s[t] - v;  // exclusive
}

__global__ void scan3_kernel(int* __restrict__ row_start, int* __restrict__ cursor,
                             const int* __restrict__ blockOffsets, int n, int E) {
    int gid = blockIdx.x * SCAN_B + threadIdx.x;
    if (gid < n) {
        int v = row_start[gid] + blockOffsets[blockIdx.x];
        row_start[gid] = v;
        cursor[gid] = v;
    }
    if (gid == 0) row_start[n] = E;
}

// ---- CSR fill with fused per-edge coefficient ----
__global__ void fill_kernel(const int* __restrict__ src, const int* __restrict__ dst,
                            const float* __restrict__ ew, const float* __restrict__ dinv,
                            int* __restrict__ cursor, int* __restrict__ esrc,
                            float* __restrict__ ecoef, int E) {
    int e = blockIdx.x * 256 + threadIdx.x;
    if (e < E) {
        int s = src[e], d = dst[e];
        int pos = atomicAdd(&cursor[d], 1);
        esrc[pos] = s;
        ecoef[pos] = dinv[s] * ew[e] * dinv[d];
    }
}

// ---- fp32 tiled GEMM: C[n x 256] = A[n x 256] @ W[256 x 256] ----
#define BM 64
#define BN 64
#define BK 16
__global__ __launch_bounds__(256) void gemm_kernel(const float* __restrict__ A,
                                                   const float* __restrict__ W,
                                                   float* __restrict__ C, int n) {
    __shared__ float As[BK][BM + 1];
    __shared__ float Bs[BK][BN + 1];
    int t = threadIdx.x;
    int bm = blockIdx.x * BM;
    int bn = blockIdx.y * BN;
    int tx = t & 15, ty = t >> 4;
    float acc[4][4] = {};
    for (int k0 = 0; k0 < D; k0 += BK) {
        #pragma unroll
        for (int i = 0; i < 4; i++) {
            int idx = t + i * 256;       // 0..1023
            int m = idx >> 4;
            int kk = idx & 15;
            int row = bm + m;
            As[kk][m] = (row < n) ? A[row * D + k0 + kk] : 0.0f;
        }
        #pragma unroll
        for (int i = 0; i < 4; i++) {
            int idx = t + i * 256;
            int kk = idx >> 6;
            int nn = idx & 63;
            Bs[kk][nn] = W[(k0 + kk) * D + bn + nn];
        }
        __syncthreads();
        #pragma unroll
        for (int kk = 0; kk < BK; kk++) {
            float a[4], b[4];
            #pragma unroll
            for (int j = 0; j < 4; j++) a[j] = As[kk][ty + 16 * j];
            #pragma unroll
            for (int l = 0; l < 4; l++) b[l] = Bs[kk][tx + 16 * l];
            #pragma unroll
            for (int j = 0; j < 4; j++)
                #pragma unroll
                for (int l = 0; l < 4; l++)
                    acc[j][l] += a[j] * b[l];
        }
        __syncthreads();
    }
    #pragma unroll
    for (int j = 0; j < 4; j++) {
        int row = bm + ty + 16 * j;
        if (row >= n) continue;
        #pragma unroll
        for (int l = 0; l < 4; l++)
            C[row * D + bn + tx + 16 * l] = acc[j][l];
    }
}

// ---- gather: one block per node, thread = channel ----
template <bool RELU>
__global__ __launch_bounds__(256) void gather_kernel(const float* __restrict__ xw,
                                                     const int* __restrict__ row_start,
                                                     const int* __restrict__ esrc,
                                                     const float* __restrict__ ecoef,
                                                     const float* __restrict__ dinv,
                                                     const float* __restrict__ bias,
                                                     float* __restrict__ out) {
    __shared__ int s_src[256];
    __shared__ float s_coef[256];
    int i = blockIdx.x;
    int c = threadIdx.x;
    float di = dinv[i];
    float acc = di * di * xw[(size_t)i * D + c] + bias[c];
    int beg = row_start[i], end = row_start[i + 1];
    for (int base = beg; base < end; base += 256) {
        int cnt = min(256, end - base);
        if (c < cnt) {
            s_src[c] = esrc[base + c];
            s_coef[c] = ecoef[base + c];
        }
        __syncthreads();
        for (int e = 0; e < cnt; e++) {
            acc += s_coef[e] * xw[(size_t)s_src[e] * D + c];
        }
        __syncthreads();
    }
    out[(size_t)i * D + c] = RELU ? fmaxf(acc, 0.0f) : acc;
}

extern "C" void kernel_launch(void* const* d_in, const int* in_sizes, int n_in,
                              void* d_out, int out_size, void* d_ws, size_t ws_size,
                              hipStream_t stream) {
    const float* x  = (const float*)d_in[0];
    const int*   ei = (const int*)d_in[1];
    const float* ew = (const float*)d_in[2];
    const float* W1 = (const float*)d_in[3];
    const float* b1 = (const float*)d_in[4];
    const float* W2 = (const float*)d_in[5];
    const float* b2 = (const float*)d_in[6];
    float* out = (float*)d_out;

    const int n = in_sizes[0] / D;     // 50000
    const int E = in_sizes[2];         // 1e6
    const int* src = ei;
    const int* dst = ei + E;

    // workspace carve-up (256B aligned)
    char* ws = (char*)d_ws;
    size_t off = 0;
    auto carve = [&](size_t bytes) {
        char* p = ws + off;
        off = (off + bytes + 255) & ~(size_t)255;
        return p;
    };
    float* dinv        = (float*)carve((size_t)n * 4);        // deg then dinv in-place
    int*   counts      = (int*)carve((size_t)n * 4);
    int*   row_start   = (int*)carve((size_t)(n + 1) * 4);
    int*   cursor      = (int*)carve((size_t)n * 4);
    int*   blockSums   = (int*)carve(128 * 4);
    int*   blockOffsets= (int*)carve(128 * 4);
    int*   esrc        = (int*)carve((size_t)E * 4);
    float* ecoef       = (float*)carve((size_t)E * 4);
    float* xw          = (float*)carve((size_t)n * D * 4);
    float* h           = (float*)carve((size_t)n * D * 4);

    const int nb_scan = (n + SCAN_B - 1) / SCAN_B;
    const int nb_edge = (E + 255) / 256;
    const int nb_node = (n + 255) / 256;

    hipMemsetAsync(dinv, 0, (size_t)n * 4, stream);
    hipMemsetAsync(counts, 0, (size_t)n * 4, stream);

    pass1_kernel<<<nb_edge, 256, 0, stream>>>(dst, ew, dinv, counts, E);
    dinv_kernel<<<nb_node, 256, 0, stream>>>(dinv, n);
    scan1_kernel<<<nb_scan, SCAN_B, 0, stream>>>(counts, row_start, blockSums, n);
    scan2_kernel<<<1, 128, 0, stream>>>(blockSums, blockOffsets, nb_scan);
    scan3_kernel<<<nb_scan, SCAN_B, 0, stream>>>(row_start, cursor, blockOffsets, n, E);
    fill_kernel<<<nb_edge, 256, 0, stream>>>(src, dst, ew, dinv, cursor, esrc, ecoef, E);

    dim3 ggrid((n + BM - 1) / BM, D / BN);
    // layer 1
    gemm_kernel<<<ggrid, 256, 0, stream>>>(x, W1, xw, n);
    gather_kernel<true><<<n, 256, 0, stream>>>(xw, row_start, esrc, ecoef, dinv, b1, h);
    // layer 2
    gemm_kernel<<<ggrid, 256, 0, stream>>>(h, W2, xw, n);
    gather_kernel<false><<<n, 256, 0, stream>>>(xw, row_start, esrc, ecoef, dinv, b2, out);
}

// Round 2
// 479.260 us; speedup vs baseline: 1.6947x; 1.6947x over previous
//
#include <hip/hip_runtime.h>
#include <hip/hip_bf16.h>
#include <stdint.h>

// GCN 2-layer forward: N=50000, E=1e6, D=256.
// Round 2: bf16 MFMA GEMM (16x16x32) + bf16 xw storage for gather traffic.

#define D 256
#define SCAN_B 512

typedef __attribute__((ext_vector_type(8))) short short8;
typedef __attribute__((ext_vector_type(4))) float floatx4;

__device__ inline unsigned short f2bf_rne(float f) {
    union { float f; uint32_t u; } v; v.f = f;
    uint32_t u = v.u;
    return (unsigned short)((u + 0x7FFFu + ((u >> 16) & 1u)) >> 16);
}
__device__ inline float bf_lo(uint32_t u) { union { uint32_t u; float f; } v; v.u = u << 16; return v.f; }
__device__ inline float bf_hi(uint32_t u) { union { uint32_t u; float f; } v; v.u = u & 0xFFFF0000u; return v.f; }

// ---- degree + per-dst counts ----
__global__ void pass1_kernel(const int* __restrict__ dst, const float* __restrict__ ew,
                             float* __restrict__ deg, int* __restrict__ counts, int E) {
    int e = blockIdx.x * 256 + threadIdx.x;
    if (e < E) {
        int d = dst[e];
        atomicAdd(&deg[d], ew[e]);
        atomicAdd(&counts[d], 1);
    }
}

__global__ void dinv_kernel(float* __restrict__ deg_dinv, int n) {
    int i = blockIdx.x * 256 + threadIdx.x;
    if (i < n) {
        float d = deg_dinv[i] + 1.0f;   // self-loop weight 1
        deg_dinv[i] = (d > 0.0f) ? rsqrtf(d) : 0.0f;
    }
}

// ---- hierarchical exclusive scan ----
__global__ void scan1_kernel(const int* __restrict__ counts, int* __restrict__ row_start,
                             int* __restrict__ blockSums, int n) {
    __shared__ int s[SCAN_B];
    int t = threadIdx.x;
    int gid = blockIdx.x * SCAN_B + t;
    int v = (gid < n) ? counts[gid] : 0;
    s[t] = v;
    __syncthreads();
    for (int off = 1; off < SCAN_B; off <<= 1) {
        int add = (t >= off) ? s[t - off] : 0;
        __syncthreads();
        s[t] += add;
        __syncthreads();
    }
    if (gid < n) row_start[gid] = s[t] - v;
    if (t == SCAN_B - 1) blockSums[blockIdx.x] = s[SCAN_B - 1];
}

__global__ void scan2_kernel(const int* __restrict__ blockSums, int* __restrict__ blockOffsets, int nb) {
    __shared__ int s[128];
    int t = threadIdx.x;
    int v = (t < nb) ? blockSums[t] : 0;
    s[t] = v;
    __syncthreads();
    for (int off = 1; off < 128; off <<= 1) {
        int add = (t >= off) ? s[t - off] : 0;
        __syncthreads();
        s[t] += add;
        __syncthreads();
    }
    if (t < nb) blockOffsets[t] = s[t] - v;
}

__global__ void scan3_kernel(int* __restrict__ row_start, int* __restrict__ cursor,
                             const int* __restrict__ blockOffsets, int n, int E) {
    int gid = blockIdx.x * SCAN_B + threadIdx.x;
    if (gid < n) {
        int v = row_start[gid] + blockOffsets[blockIdx.x];
        row_start[gid] = v;
        cursor[gid] = v;
    }
    if (gid == 0) row_start[n] = E;
}

// ---- CSR fill with fused coefficient ----
__global__ void fill_kernel(const int* __restrict__ src, const int* __restrict__ dst,
                            const float* __restrict__ ew, const float* __restrict__ dinv,
                            int* __restrict__ cursor, int* __restrict__ esrc,
                            float* __restrict__ ecoef, int E) {
    int e = blockIdx.x * 256 + threadIdx.x;
    if (e < E) {
        int s = src[e], d = dst[e];
        int pos = atomicAdd(&cursor[d], 1);
        esrc[pos] = s;
        ecoef[pos] = dinv[s] * ew[e] * dinv[d];
    }
}

// ---- fp32 -> bf16 pair-packed ----
__global__ void cvt_x_kernel(const float* __restrict__ in, uint32_t* __restrict__ out, int n2) {
    int i = blockIdx.x * 256 + threadIdx.x;
    if (i < n2) {
        float2 f = ((const float2*)in)[i];
        out[i] = (uint32_t)f2bf_rne(f.x) | ((uint32_t)f2bf_rne(f.y) << 16);
    }
}

// ---- W [k][n] fp32 -> Wt [n][k] bf16 (LDS transpose) ----
__global__ __launch_bounds__(1024) void cvt_wT_kernel(const float* __restrict__ W,
                                                      unsigned short* __restrict__ Wt) {
    __shared__ float s[32][33];
    int k0 = blockIdx.y * 32, n0 = blockIdx.x * 32;
    int tx = threadIdx.x, ty = threadIdx.y;
    s[ty][tx] = W[(k0 + ty) * D + n0 + tx];
    __syncthreads();
    Wt[(n0 + ty) * D + k0 + tx] = f2bf_rne(s[tx][ty]);
}

// ---- bf16 MFMA GEMM: C[n x 256] = A[n x 256] @ W, W given transposed [n][k] ----
#define GBM 128
#define GBN 128
#define GBK 32
#define LDA 40   // padded LDS row length (bf16 elems): 80B, 16B-aligned, bank-spread

__global__ __launch_bounds__(256) void gemm_bf16_kernel(const unsigned short* __restrict__ A,
                                                        const unsigned short* __restrict__ Bt,
                                                        unsigned short* __restrict__ C, int n) {
    __shared__ unsigned short As[GBM][LDA];
    __shared__ unsigned short Bs[GBN][LDA];
    int t = threadIdx.x;
    int bm = blockIdx.x * GBM;
    int bn = blockIdx.y * GBN;
    int w = t >> 6, l = t & 63;
    int wm = (w >> 1) * 64, wn = (w & 1) * 64;
    int lr = l & 15;   // lane row-in-16 (A: m, B: n, C: col)
    int lq = l >> 4;   // quad (k-offset lq*8; C: row lq*4+r)
    floatx4 acc[4][4] = {};
    for (int k0 = 0; k0 < D; k0 += GBK) {
        #pragma unroll
        for (int i = 0; i < 2; i++) {
            int c = t + i * 256;          // 0..511 chunk id
            int row = c >> 2;             // 128 rows x 4 chunks
            int kk = (c & 3) * 8;
            int gr = bm + row;
            short8 av = {};
            if (gr < n) av = *(const short8*)&A[(size_t)gr * D + k0 + kk];
            *(short8*)&As[row][kk] = av;
            short8 bv = *(const short8*)&Bt[(size_t)(bn + row) * D + k0 + kk];
            *(short8*)&Bs[row][kk] = bv;
        }
        __syncthreads();
        short8 af[4], bfr[4];
        #pragma unroll
        for (int i = 0; i < 4; i++) af[i] = *(const short8*)&As[wm + i * 16 + lr][lq * 8];
        #pragma unroll
        for (int j = 0; j < 4; j++) bfr[j] = *(const short8*)&Bs[wn + j * 16 + lr][lq * 8];
        #pragma unroll
        for (int i = 0; i < 4; i++)
            #pragma unroll
            for (int j = 0; j < 4; j++)
                acc[i][j] = __builtin_amdgcn_mfma_f32_16x16x32_bf16(af[i], bfr[j], acc[i][j], 0, 0, 0);
        __syncthreads();
    }
    #pragma unroll
    for (int i = 0; i < 4; i++) {
        #pragma unroll
        for (int r = 0; r < 4; r++) {
            int row = bm + wm + i * 16 + lq * 4 + r;
            if (row >= n) continue;
            #pragma unroll
            for (int j = 0; j < 4; j++) {
                int col = bn + wn + j * 16 + lr;
                C[(size_t)row * D + col] = f2bf_rne(acc[i][j][r]);
            }
        }
    }
}

// ---- gather: one block (128 thr) per node, thread = channel pair ----
template <bool RELU, bool OUT_BF16>
__global__ __launch_bounds__(128) void gather_kernel(const uint32_t* __restrict__ xwb,  // n x 128 dwords (bf16 pairs)
                                                     const int* __restrict__ row_start,
                                                     const int* __restrict__ esrc,
                                                     const float* __restrict__ ecoef,
                                                     const float* __restrict__ dinv,
                                                     const float* __restrict__ bias,
                                                     void* __restrict__ outv) {
    __shared__ int s_src[128];
    __shared__ float s_coef[128];
    int i = blockIdx.x;
    int t = threadIdx.x;
    float di = dinv[i];
    float ws = di * di;
    uint32_t u0 = xwb[(size_t)i * 128 + t];
    float2 bb = ((const float2*)bias)[t];
    float2 acc;
    acc.x = ws * bf_lo(u0) + bb.x;
    acc.y = ws * bf_hi(u0) + bb.y;
    int beg = row_start[i], end = row_start[i + 1];
    for (int base = beg; base < end; base += 128) {
        int cnt = min(128, end - base);
        if (t < cnt) {
            s_src[t] = esrc[base + t];
            s_coef[t] = ecoef[base + t];
        }
        __syncthreads();
        for (int e = 0; e < cnt; e++) {
            uint32_t u = xwb[(size_t)s_src[e] * 128 + t];
            float cf = s_coef[e];
            acc.x += cf * bf_lo(u);
            acc.y += cf * bf_hi(u);
        }
        __syncthreads();
    }
    if (RELU) {
        acc.x = fmaxf(acc.x, 0.0f);
        acc.y = fmaxf(acc.y, 0.0f);
    }
    if (OUT_BF16) {
        ((uint32_t*)outv)[(size_t)i * 128 + t] =
            (uint32_t)f2bf_rne(acc.x) | ((uint32_t)f2bf_rne(acc.y) << 16);
    } else {
        ((float2*)outv)[(size_t)i * 128 + t] = acc;
    }
}

extern "C" void kernel_launch(void* const* d_in, const int* in_sizes, int n_in,
                              void* d_out, int out_size, void* d_ws, size_t ws_size,
                              hipStream_t stream) {
    const float* x  = (const float*)d_in[0];
    const int*   ei = (const int*)d_in[1];
    const float* ew = (const float*)d_in[2];
    const float* W1 = (const float*)d_in[3];
    const float* b1 = (const float*)d_in[4];
    const float* W2 = (const float*)d_in[5];
    const float* b2 = (const float*)d_in[6];
    float* out = (float*)d_out;

    const int n = in_sizes[0] / D;     // 50000
    const int E = in_sizes[2];         // 1e6
    const int* src = ei;
    const int* dst = ei + E;

    char* ws = (char*)d_ws;
    size_t off = 0;
    auto carve = [&](size_t bytes) {
        char* p = ws + off;
        off = (off + bytes + 255) & ~(size_t)255;
        return p;
    };
    float* dinv        = (float*)carve((size_t)n * 4);
    int*   counts      = (int*)carve((size_t)n * 4);
    int*   row_start   = (int*)carve((size_t)(n + 1) * 4);
    int*   cursor      = (int*)carve((size_t)n * 4);
    int*   blockSums   = (int*)carve(128 * 4);
    int*   blockOffsets= (int*)carve(128 * 4);
    int*   esrc        = (int*)carve((size_t)E * 4);
    float* ecoef       = (float*)carve((size_t)E * 4);
    unsigned short* xb  = (unsigned short*)carve((size_t)n * D * 2);
    unsigned short* w1t = (unsigned short*)carve((size_t)D * D * 2);
    unsigned short* w2t = (unsigned short*)carve((size_t)D * D * 2);
    unsigned short* xwb = (unsigned short*)carve((size_t)n * D * 2);
    unsigned short* hb  = (unsigned short*)carve((size_t)n * D * 2);

    const int nb_scan = (n + SCAN_B - 1) / SCAN_B;
    const int nb_edge = (E + 255) / 256;
    const int nb_node = (n + 255) / 256;

    hipMemsetAsync(dinv, 0, (size_t)n * 4, stream);
    hipMemsetAsync(counts, 0, (size_t)n * 4, stream);

    pass1_kernel<<<nb_edge, 256, 0, stream>>>(dst, ew, dinv, counts, E);
    dinv_kernel<<<nb_node, 256, 0, stream>>>(dinv, n);
    scan1_kernel<<<nb_scan, SCAN_B, 0, stream>>>(counts, row_start, blockSums, n);
    scan2_kernel<<<1, 128, 0, stream>>>(blockSums, blockOffsets, nb_scan);
    scan3_kernel<<<nb_scan, SCAN_B, 0, stream>>>(row_start, cursor, blockOffsets, n, E);
    fill_kernel<<<nb_edge, 256, 0, stream>>>(src, dst, ew, dinv, cursor, esrc, ecoef, E);

    // conversions
    int n2 = n * D / 2;
    cvt_x_kernel<<<(n2 + 255) / 256, 256, 0, stream>>>(x, (uint32_t*)xb, n2);
    cvt_wT_kernel<<<dim3(8, 8), dim3(32, 32), 0, stream>>>(W1, w1t);
    cvt_wT_kernel<<<dim3(8, 8), dim3(32, 32), 0, stream>>>(W2, w2t);

    dim3 ggrid((n + GBM - 1) / GBM, D / GBN);
    // layer 1
    gemm_bf16_kernel<<<ggrid, 256, 0, stream>>>(xb, w1t, xwb, n);
    gather_kernel<true, true><<<n, 128, 0, stream>>>((const uint32_t*)xwb, row_start, esrc, ecoef,
                                                     dinv, b1, hb);
    // layer 2
    gemm_bf16_kernel<<<ggrid, 256, 0, stream>>>(hb, w2t, xwb, n);
    gather_kernel<false, false><<<n, 128, 0, stream>>>((const uint32_t*)xwb, row_start, esrc, ecoef,
                                                       dinv, b2, out);
}

// Round 3
// 405.870 us; speedup vs baseline: 2.0011x; 1.1808x over previous
//
#include <hip/hip_runtime.h>
#include <hip/hip_bf16.h>
#include <stdint.h>

// GCN 2-layer forward: N=50000, E=1e6, D=256.
// Round 3: single packed 64-bit atomic for (count, deg-fixedpoint) + rank
// reuse makes fill atomic-free; gather uses scalar loads, no LDS.

#define D 256
#define SCAN_B 512

typedef __attribute__((ext_vector_type(8))) short short8;
typedef __attribute__((ext_vector_type(4))) float floatx4;

__device__ inline unsigned short f2bf_rne(float f) {
    union { float f; uint32_t u; } v; v.f = f;
    uint32_t u = v.u;
    return (unsigned short)((u + 0x7FFFu + ((u >> 16) & 1u)) >> 16);
}
__device__ inline float bf_lo(uint32_t u) { union { uint32_t u; float f; } v; v.u = u << 16; return v.f; }
__device__ inline float bf_hi(uint32_t u) { union { uint32_t u; float f; } v; v.u = u & 0xFFFF0000u; return v.f; }

#define FXS 16777216.0f   // 2^24 fixed-point scale for edge weights

// ---- pass1: one 64-bit atomic per edge: hi32 = ew fixed-point sum, lo32 = count.
//      Returned old low word = this edge's rank within its dst bucket.
__global__ void pass1_kernel(const int* __restrict__ dst, const float* __restrict__ ew,
                             unsigned long long* __restrict__ packed,
                             int* __restrict__ rank, int E) {
    int e = blockIdx.x * 256 + threadIdx.x;
    if (e < E) {
        int d = dst[e];
        uint32_t fx = __float2uint_rn(ew[e] * FXS);
        unsigned long long old =
            atomicAdd(&packed[d], ((unsigned long long)fx << 32) | 1ull);
        rank[e] = (int)(uint32_t)old;
    }
}

// ---- unpack: counts + dinv from packed ----
__global__ void unpack_kernel(const unsigned long long* __restrict__ packed,
                              int* __restrict__ counts, float* __restrict__ dinv, int n) {
    int i = blockIdx.x * 256 + threadIdx.x;
    if (i < n) {
        unsigned long long p = packed[i];
        counts[i] = (int)(uint32_t)p;
        float deg = (float)(p >> 32) * (1.0f / FXS) + 1.0f;   // +1 self-loop; always > 0
        dinv[i] = rsqrtf(deg);
    }
}

// ---- hierarchical exclusive scan ----
__global__ void scan1_kernel(const int* __restrict__ counts, int* __restrict__ row_start,
                             int* __restrict__ blockSums, int n) {
    __shared__ int s[SCAN_B];
    int t = threadIdx.x;
    int gid = blockIdx.x * SCAN_B + t;
    int v = (gid < n) ? counts[gid] : 0;
    s[t] = v;
    __syncthreads();
    for (int off = 1; off < SCAN_B; off <<= 1) {
        int add = (t >= off) ? s[t - off] : 0;
        __syncthreads();
        s[t] += add;
        __syncthreads();
    }
    if (gid < n) row_start[gid] = s[t] - v;
    if (t == SCAN_B - 1) blockSums[blockIdx.x] = s[SCAN_B - 1];
}

__global__ void scan2_kernel(const int* __restrict__ blockSums, int* __restrict__ blockOffsets, int nb) {
    __shared__ int s[128];
    int t = threadIdx.x;
    int v = (t < nb) ? blockSums[t] : 0;
    s[t] = v;
    __syncthreads();
    for (int off = 1; off < 128; off <<= 1) {
        int add = (t >= off) ? s[t - off] : 0;
        __syncthreads();
        s[t] += add;
        __syncthreads();
    }
    if (t < nb) blockOffsets[t] = s[t] - v;
}

__global__ void scan3_kernel(int* __restrict__ row_start,
                             const int* __restrict__ blockOffsets, int n, int E) {
    int gid = blockIdx.x * SCAN_B + threadIdx.x;
    if (gid < n) row_start[gid] += blockOffsets[blockIdx.x];
    if (gid == 0) row_start[n] = E;
}

// ---- CSR fill, atomic-free: pos = row_start[dst] + rank ----
__global__ void fill_kernel(const int* __restrict__ src, const int* __restrict__ dst,
                            const float* __restrict__ ew, const int* __restrict__ rank,
                            const int* __restrict__ row_start, const float* __restrict__ dinv,
                            int* __restrict__ esrc, float* __restrict__ ecoef, int E) {
    int e = blockIdx.x * 256 + threadIdx.x;
    if (e < E) {
        int s = src[e], d = dst[e];
        int pos = row_start[d] + rank[e];
        esrc[pos] = s;
        ecoef[pos] = dinv[s] * ew[e] * dinv[d];
    }
}

// ---- fp32 -> bf16 pair-packed ----
__global__ void cvt_x_kernel(const float* __restrict__ in, uint32_t* __restrict__ out, int n2) {
    int i = blockIdx.x * 256 + threadIdx.x;
    if (i < n2) {
        float2 f = ((const float2*)in)[i];
        out[i] = (uint32_t)f2bf_rne(f.x) | ((uint32_t)f2bf_rne(f.y) << 16);
    }
}

// ---- W [k][n] fp32 -> Wt [n][k] bf16 (LDS transpose) ----
__global__ __launch_bounds__(1024) void cvt_wT_kernel(const float* __restrict__ W,
                                                      unsigned short* __restrict__ Wt) {
    __shared__ float s[32][33];
    int k0 = blockIdx.y * 32, n0 = blockIdx.x * 32;
    int tx = threadIdx.x, ty = threadIdx.y;
    s[ty][tx] = W[(k0 + ty) * D + n0 + tx];
    __syncthreads();
    Wt[(n0 + ty) * D + k0 + tx] = f2bf_rne(s[tx][ty]);
}

// ---- bf16 MFMA GEMM: C[n x 256] = A[n x 256] @ W, W given transposed [n][k] ----
#define GBM 128
#define GBN 128
#define GBK 32
#define LDA 40

__global__ __launch_bounds__(256) void gemm_bf16_kernel(const unsigned short* __restrict__ A,
                                                        const unsigned short* __restrict__ Bt,
                                                        unsigned short* __restrict__ C, int n) {
    __shared__ unsigned short As[GBM][LDA];
    __shared__ unsigned short Bs[GBN][LDA];
    int t = threadIdx.x;
    int bm = blockIdx.x * GBM;
    int bn = blockIdx.y * GBN;
    int w = t >> 6, l = t & 63;
    int wm = (w >> 1) * 64, wn = (w & 1) * 64;
    int lr = l & 15;
    int lq = l >> 4;
    floatx4 acc[4][4] = {};
    for (int k0 = 0; k0 < D; k0 += GBK) {
        #pragma unroll
        for (int i = 0; i < 2; i++) {
            int c = t + i * 256;
            int row = c >> 2;
            int kk = (c & 3) * 8;
            int gr = bm + row;
            short8 av = {};
            if (gr < n) av = *(const short8*)&A[(size_t)gr * D + k0 + kk];
            *(short8*)&As[row][kk] = av;
            short8 bv = *(const short8*)&Bt[(size_t)(bn + row) * D + k0 + kk];
            *(short8*)&Bs[row][kk] = bv;
        }
        __syncthreads();
        short8 af[4], bfr[4];
        #pragma unroll
        for (int i = 0; i < 4; i++) af[i] = *(const short8*)&As[wm + i * 16 + lr][lq * 8];
        #pragma unroll
        for (int j = 0; j < 4; j++) bfr[j] = *(const short8*)&Bs[wn + j * 16 + lr][lq * 8];
        #pragma unroll
        for (int i = 0; i < 4; i++)
            #pragma unroll
            for (int j = 0; j < 4; j++)
                acc[i][j] = __builtin_amdgcn_mfma_f32_16x16x32_bf16(af[i], bfr[j], acc[i][j], 0, 0, 0);
        __syncthreads();
    }
    #pragma unroll
    for (int i = 0; i < 4; i++) {
        #pragma unroll
        for (int r = 0; r < 4; r++) {
            int row = bm + wm + i * 16 + lq * 4 + r;
            if (row >= n) continue;
            #pragma unroll
            for (int j = 0; j < 4; j++) {
                int col = bn + wn + j * 16 + lr;
                C[(size_t)row * D + col] = f2bf_rne(acc[i][j][r]);
            }
        }
    }
}

// ---- gather: one block (128 thr) per node; esrc/ecoef via uniform scalar loads ----
template <bool RELU, bool OUT_BF16>
__global__ __launch_bounds__(128) void gather_kernel(const uint32_t* __restrict__ xwb,
                                                     const int* __restrict__ row_start,
                                                     const int* __restrict__ esrc,
                                                     const float* __restrict__ ecoef,
                                                     const float* __restrict__ dinv,
                                                     const float* __restrict__ bias,
                                                     void* __restrict__ outv) {
    int i = blockIdx.x;
    int t = threadIdx.x;
    float di = dinv[i];
    float ws = di * di;
    uint32_t u0 = xwb[(size_t)i * 128 + t];
    float2 bb = ((const float2*)bias)[t];
    float2 a0, a1;
    a0.x = ws * bf_lo(u0) + bb.x;
    a0.y = ws * bf_hi(u0) + bb.y;
    a1.x = 0.0f; a1.y = 0.0f;
    int beg = row_start[i], end = row_start[i + 1];
    int j = beg;
    for (; j + 2 <= end; j += 2) {
        int   s0 = esrc[j],     s1 = esrc[j + 1];
        float c0 = ecoef[j],    c1 = ecoef[j + 1];
        uint32_t v0 = xwb[(size_t)s0 * 128 + t];
        uint32_t v1 = xwb[(size_t)s1 * 128 + t];
        a0.x += c0 * bf_lo(v0); a0.y += c0 * bf_hi(v0);
        a1.x += c1 * bf_lo(v1); a1.y += c1 * bf_hi(v1);
    }
    if (j < end) {
        int s0 = esrc[j];
        float c0 = ecoef[j];
        uint32_t v0 = xwb[(size_t)s0 * 128 + t];
        a0.x += c0 * bf_lo(v0); a0.y += c0 * bf_hi(v0);
    }
    float2 acc;
    acc.x = a0.x + a1.x;
    acc.y = a0.y + a1.y;
    if (RELU) {
        acc.x = fmaxf(acc.x, 0.0f);
        acc.y = fmaxf(acc.y, 0.0f);
    }
    if (OUT_BF16) {
        ((uint32_t*)outv)[(size_t)i * 128 + t] =
            (uint32_t)f2bf_rne(acc.x) | ((uint32_t)f2bf_rne(acc.y) << 16);
    } else {
        ((float2*)outv)[(size_t)i * 128 + t] = acc;
    }
}

extern "C" void kernel_launch(void* const* d_in, const int* in_sizes, int n_in,
                              void* d_out, int out_size, void* d_ws, size_t ws_size,
                              hipStream_t stream) {
    const float* x  = (const float*)d_in[0];
    const int*   ei = (const int*)d_in[1];
    const float* ew = (const float*)d_in[2];
    const float* W1 = (const float*)d_in[3];
    const float* b1 = (const float*)d_in[4];
    const float* W2 = (const float*)d_in[5];
    const float* b2 = (const float*)d_in[6];
    float* out = (float*)d_out;

    const int n = in_sizes[0] / D;     // 50000
    const int E = in_sizes[2];         // 1e6
    const int* src = ei;
    const int* dst = ei + E;

    char* ws = (char*)d_ws;
    size_t off = 0;
    auto carve = [&](size_t bytes) {
        char* p = ws + off;
        off = (off + bytes + 255) & ~(size_t)255;
        return p;
    };
    unsigned long long* packed = (unsigned long long*)carve((size_t)n * 8);
    float* dinv        = (float*)carve((size_t)n * 4);
    int*   counts      = (int*)carve((size_t)n * 4);
    int*   row_start   = (int*)carve((size_t)(n + 1) * 4);
    int*   blockSums   = (int*)carve(128 * 4);
    int*   blockOffsets= (int*)carve(128 * 4);
    int*   rank        = (int*)carve((size_t)E * 4);
    int*   esrc        = (int*)carve((size_t)E * 4);
    float* ecoef       = (float*)carve((size_t)E * 4);
    unsigned short* xb  = (unsigned short*)carve((size_t)n * D * 2);
    unsigned short* w1t = (unsigned short*)carve((size_t)D * D * 2);
    unsigned short* w2t = (unsigned short*)carve((size_t)D * D * 2);
    unsigned short* xwb = (unsigned short*)carve((size_t)n * D * 2);
    unsigned short* hb  = (unsigned short*)carve((size_t)n * D * 2);

    const int nb_scan = (n + SCAN_B - 1) / SCAN_B;
    const int nb_edge = (E + 255) / 256;
    const int nb_node = (n + 255) / 256;

    hipMemsetAsync(packed, 0, (size_t)n * 8, stream);

    pass1_kernel<<<nb_edge, 256, 0, stream>>>(dst, ew, packed, rank, E);
    unpack_kernel<<<nb_node, 256, 0, stream>>>(packed, counts, dinv, n);
    scan1_kernel<<<nb_scan, SCAN_B, 0, stream>>>(counts, row_start, blockSums, n);
    scan2_kernel<<<1, 128, 0, stream>>>(blockSums, blockOffsets, nb_scan);
    scan3_kernel<<<nb_scan, SCAN_B, 0, stream>>>(row_start, blockOffsets, n, E);
    fill_kernel<<<nb_edge, 256, 0, stream>>>(src, dst, ew, rank, row_start, dinv, esrc, ecoef, E);

    // conversions
    int n2 = n * D / 2;
    cvt_x_kernel<<<(n2 + 255) / 256, 256, 0, stream>>>(x, (uint32_t*)xb, n2);
    cvt_wT_kernel<<<dim3(8, 8), dim3(32, 32), 0, stream>>>(W1, w1t);
    cvt_wT_kernel<<<dim3(8, 8), dim3(32, 32), 0, stream>>>(W2, w2t);

    dim3 ggrid((n + GBM - 1) / GBM, D / GBN);
    // layer 1
    gemm_bf16_kernel<<<ggrid, 256, 0, stream>>>(xb, w1t, xwb, n);
    gather_kernel<true, true><<<n, 128, 0, stream>>>((const uint32_t*)xwb, row_start, esrc, ecoef,
                                                     dinv, b1, hb);
    // layer 2
    gemm_bf16_kernel<<<ggrid, 256, 0, stream>>>(hb, w2t, xwb, n);
    gather_kernel<false, false><<<n, 128, 0, stream>>>((const uint32_t*)xwb, row_start, esrc, ecoef,
                                                       dinv, b2, out);
}

// Round 4
// 386.828 us; speedup vs baseline: 2.0996x; 1.0492x over previous
//
#include <hip/hip_runtime.h>
#include <hip/hip_bf16.h>
#include <stdint.h>

// GCN 2-layer forward: N=50000, E=1e6, D=256.
// Round 4: wave-per-node gather (dwordx2/lane, unroll-4 clamped, scalar edge
// metadata), fp32->bf16 conversion fused into GEMM-1 staging.

#define D 256
#define SCAN_B 512

typedef __attribute__((ext_vector_type(8))) short short8;
typedef __attribute__((ext_vector_type(4))) float floatx4;

__device__ inline unsigned short f2bf_rne(float f) {
    union { float f; uint32_t u; } v; v.f = f;
    uint32_t u = v.u;
    return (unsigned short)((u + 0x7FFFu + ((u >> 16) & 1u)) >> 16);
}
__device__ inline float bf_lo(uint32_t u) { union { uint32_t u; float f; } v; v.u = u << 16; return v.f; }
__device__ inline float bf_hi(uint32_t u) { union { uint32_t u; float f; } v; v.u = u & 0xFFFF0000u; return v.f; }

#define FXS 16777216.0f   // 2^24 fixed-point scale for edge weights

// ---- pass1: one 64-bit atomic per edge: hi32 = ew fixed-point sum, lo32 = count.
__global__ void pass1_kernel(const int* __restrict__ dst, const float* __restrict__ ew,
                             unsigned long long* __restrict__ packed,
                             int* __restrict__ rank, int E) {
    int e = blockIdx.x * 256 + threadIdx.x;
    if (e < E) {
        int d = dst[e];
        uint32_t fx = __float2uint_rn(ew[e] * FXS);
        unsigned long long old =
            atomicAdd(&packed[d], ((unsigned long long)fx << 32) | 1ull);
        rank[e] = (int)(uint32_t)old;
    }
}

__global__ void unpack_kernel(const unsigned long long* __restrict__ packed,
                              int* __restrict__ counts, float* __restrict__ dinv, int n) {
    int i = blockIdx.x * 256 + threadIdx.x;
    if (i < n) {
        unsigned long long p = packed[i];
        counts[i] = (int)(uint32_t)p;
        float deg = (float)(p >> 32) * (1.0f / FXS) + 1.0f;
        dinv[i] = rsqrtf(deg);
    }
}

// ---- hierarchical exclusive scan ----
__global__ void scan1_kernel(const int* __restrict__ counts, int* __restrict__ row_start,
                             int* __restrict__ blockSums, int n) {
    __shared__ int s[SCAN_B];
    int t = threadIdx.x;
    int gid = blockIdx.x * SCAN_B + t;
    int v = (gid < n) ? counts[gid] : 0;
    s[t] = v;
    __syncthreads();
    for (int off = 1; off < SCAN_B; off <<= 1) {
        int add = (t >= off) ? s[t - off] : 0;
        __syncthreads();
        s[t] += add;
        __syncthreads();
    }
    if (gid < n) row_start[gid] = s[t] - v;
    if (t == SCAN_B - 1) blockSums[blockIdx.x] = s[SCAN_B - 1];
}

__global__ void scan2_kernel(const int* __restrict__ blockSums, int* __restrict__ blockOffsets, int nb) {
    __shared__ int s[128];
    int t = threadIdx.x;
    int v = (t < nb) ? blockSums[t] : 0;
    s[t] = v;
    __syncthreads();
    for (int off = 1; off < 128; off <<= 1) {
        int add = (t >= off) ? s[t - off] : 0;
        __syncthreads();
        s[t] += add;
        __syncthreads();
    }
    if (t < nb) blockOffsets[t] = s[t] - v;
}

__global__ void scan3_kernel(int* __restrict__ row_start,
                             const int* __restrict__ blockOffsets, int n, int E) {
    int gid = blockIdx.x * SCAN_B + threadIdx.x;
    if (gid < n) row_start[gid] += blockOffsets[blockIdx.x];
    if (gid == 0) row_start[n] = E;
}

// ---- CSR fill, atomic-free ----
__global__ void fill_kernel(const int* __restrict__ src, const int* __restrict__ dst,
                            const float* __restrict__ ew, const int* __restrict__ rank,
                            const int* __restrict__ row_start, const float* __restrict__ dinv,
                            int* __restrict__ esrc, float* __restrict__ ecoef, int E) {
    int e = blockIdx.x * 256 + threadIdx.x;
    if (e < E) {
        int s = src[e], d = dst[e];
        int pos = row_start[d] + rank[e];
        esrc[pos] = s;
        ecoef[pos] = dinv[s] * ew[e] * dinv[d];
    }
}

// ---- W [k][n] fp32 -> Wt [n][k] bf16 (both layers, z-indexed) ----
__global__ __launch_bounds__(1024) void cvt_wT_kernel(const float* __restrict__ Wa,
                                                      const float* __restrict__ Wb,
                                                      unsigned short* __restrict__ Wta,
                                                      unsigned short* __restrict__ Wtb) {
    __shared__ float s[32][33];
    const float* W = blockIdx.z ? Wb : Wa;
    unsigned short* Wt = blockIdx.z ? Wtb : Wta;
    int k0 = blockIdx.y * 32, n0 = blockIdx.x * 32;
    int tx = threadIdx.x, ty = threadIdx.y;
    s[ty][tx] = W[(k0 + ty) * D + n0 + tx];
    __syncthreads();
    Wt[(n0 + ty) * D + k0 + tx] = f2bf_rne(s[tx][ty]);
}

// ---- bf16 MFMA GEMM: C = A @ W, Wt [n][k]; A fp32 (converted in staging) or bf16 ----
#define GBM 128
#define GBN 128
#define GBK 32
#define LDA 40

template <bool AFP32>
__global__ __launch_bounds__(256) void gemm_bf16_kernel(const void* __restrict__ Ap,
                                                        const unsigned short* __restrict__ Bt,
                                                        unsigned short* __restrict__ C, int n) {
    __shared__ unsigned short As[GBM][LDA];
    __shared__ unsigned short Bs[GBN][LDA];
    int t = threadIdx.x;
    int bm = blockIdx.x * GBM;
    int bn = blockIdx.y * GBN;
    int w = t >> 6, l = t & 63;
    int wm = (w >> 1) * 64, wn = (w & 1) * 64;
    int lr = l & 15;
    int lq = l >> 4;
    floatx4 acc[4][4] = {};
    for (int k0 = 0; k0 < D; k0 += GBK) {
        #pragma unroll
        for (int i = 0; i < 2; i++) {
            int c = t + i * 256;
            int row = c >> 2;
            int kk = (c & 3) * 8;
            int gr = bm + row;
            short8 av = {};
            if (gr < n) {
                if (AFP32) {
                    const float* ap = (const float*)Ap + (size_t)gr * D + k0 + kk;
                    float4 f0 = *(const float4*)ap;
                    float4 f1 = *(const float4*)(ap + 4);
                    av[0] = (short)f2bf_rne(f0.x); av[1] = (short)f2bf_rne(f0.y);
                    av[2] = (short)f2bf_rne(f0.z); av[3] = (short)f2bf_rne(f0.w);
                    av[4] = (short)f2bf_rne(f1.x); av[5] = (short)f2bf_rne(f1.y);
                    av[6] = (short)f2bf_rne(f1.z); av[7] = (short)f2bf_rne(f1.w);
                } else {
                    av = *(const short8*)((const unsigned short*)Ap + (size_t)gr * D + k0 + kk);
                }
            }
            *(short8*)&As[row][kk] = av;
            short8 bv = *(const short8*)&Bt[(size_t)(bn + row) * D + k0 + kk];
            *(short8*)&Bs[row][kk] = bv;
        }
        __syncthreads();
        short8 af[4], bfr[4];
        #pragma unroll
        for (int i = 0; i < 4; i++) af[i] = *(const short8*)&As[wm + i * 16 + lr][lq * 8];
        #pragma unroll
        for (int j = 0; j < 4; j++) bfr[j] = *(const short8*)&Bs[wn + j * 16 + lr][lq * 8];
        #pragma unroll
        for (int i = 0; i < 4; i++)
            #pragma unroll
            for (int j = 0; j < 4; j++)
                acc[i][j] = __builtin_amdgcn_mfma_f32_16x16x32_bf16(af[i], bfr[j], acc[i][j], 0, 0, 0);
        __syncthreads();
    }
    #pragma unroll
    for (int i = 0; i < 4; i++) {
        #pragma unroll
        for (int r = 0; r < 4; r++) {
            int row = bm + wm + i * 16 + lq * 4 + r;
            if (row >= n) continue;
            #pragma unroll
            for (int j = 0; j < 4; j++) {
                int col = bn + wn + j * 16 + lr;
                C[(size_t)row * D + col] = f2bf_rne(acc[i][j][r]);
            }
        }
    }
}

// ---- gather: wave-per-node; lane = 4 channels (dwordx2); unroll-4 clamped ----
template <bool RELU, bool OUT_BF16>
__global__ __launch_bounds__(256) void gather_kernel(const uint2* __restrict__ xwb,  // n x 64 uint2
                                                     const int* __restrict__ row_start,
                                                     const int* __restrict__ esrc,
                                                     const float* __restrict__ ecoef,
                                                     const float* __restrict__ dinv,
                                                     const float* __restrict__ bias,
                                                     void* __restrict__ outv, int n) {
    int lane = threadIdx.x & 63;
    int i = __builtin_amdgcn_readfirstlane((blockIdx.x << 2) + (threadIdx.x >> 6));
    if (i >= n) return;
    float di = dinv[i];
    float ws = di * di;
    uint2 u0 = xwb[(size_t)i * 64 + lane];
    float4 bb = ((const float4*)bias)[lane];
    float a0 = ws * bf_lo(u0.x) + bb.x;
    float a1 = ws * bf_hi(u0.x) + bb.y;
    float a2 = ws * bf_lo(u0.y) + bb.z;
    float a3 = ws * bf_hi(u0.y) + bb.w;
    int beg = row_start[i], end = row_start[i + 1];
    for (int j = beg; j < end; j += 4) {
        int e1 = min(j + 1, end - 1), e2 = min(j + 2, end - 1), e3 = min(j + 3, end - 1);
        int s0 = esrc[j], s1 = esrc[e1], s2 = esrc[e2], s3 = esrc[e3];
        float c0 = ecoef[j];
        float c1 = (j + 1 < end) ? ecoef[e1] : 0.0f;
        float c2 = (j + 2 < end) ? ecoef[e2] : 0.0f;
        float c3 = (j + 3 < end) ? ecoef[e3] : 0.0f;
        uint2 v0 = xwb[(size_t)s0 * 64 + lane];
        uint2 v1 = xwb[(size_t)s1 * 64 + lane];
        uint2 v2 = xwb[(size_t)s2 * 64 + lane];
        uint2 v3 = xwb[(size_t)s3 * 64 + lane];
        a0 += c0 * bf_lo(v0.x); a1 += c0 * bf_hi(v0.x);
        a2 += c0 * bf_lo(v0.y); a3 += c0 * bf_hi(v0.y);
        a0 += c1 * bf_lo(v1.x); a1 += c1 * bf_hi(v1.x);
        a2 += c1 * bf_lo(v1.y); a3 += c1 * bf_hi(v1.y);
        a0 += c2 * bf_lo(v2.x); a1 += c2 * bf_hi(v2.x);
        a2 += c2 * bf_lo(v2.y); a3 += c2 * bf_hi(v2.y);
        a0 += c3 * bf_lo(v3.x); a1 += c3 * bf_hi(v3.x);
        a2 += c3 * bf_lo(v3.y); a3 += c3 * bf_hi(v3.y);
    }
    if (RELU) {
        a0 = fmaxf(a0, 0.0f); a1 = fmaxf(a1, 0.0f);
        a2 = fmaxf(a2, 0.0f); a3 = fmaxf(a3, 0.0f);
    }
    if (OUT_BF16) {
        uint2 o;
        o.x = (uint32_t)f2bf_rne(a0) | ((uint32_t)f2bf_rne(a1) << 16);
        o.y = (uint32_t)f2bf_rne(a2) | ((uint32_t)f2bf_rne(a3) << 16);
        ((uint2*)outv)[(size_t)i * 64 + lane] = o;
    } else {
        float4 o; o.x = a0; o.y = a1; o.z = a2; o.w = a3;
        ((float4*)outv)[(size_t)i * 64 + lane] = o;
    }
}

extern "C" void kernel_launch(void* const* d_in, const int* in_sizes, int n_in,
                              void* d_out, int out_size, void* d_ws, size_t ws_size,
                              hipStream_t stream) {
    const float* x  = (const float*)d_in[0];
    const int*   ei = (const int*)d_in[1];
    const float* ew = (const float*)d_in[2];
    const float* W1 = (const float*)d_in[3];
    const float* b1 = (const float*)d_in[4];
    const float* W2 = (const float*)d_in[5];
    const float* b2 = (const float*)d_in[6];
    float* out = (float*)d_out;

    const int n = in_sizes[0] / D;     // 50000
    const int E = in_sizes[2];         // 1e6
    const int* src = ei;
    const int* dst = ei + E;

    char* ws = (char*)d_ws;
    size_t off = 0;
    auto carve = [&](size_t bytes) {
        char* p = ws + off;
        off = (off + bytes + 255) & ~(size_t)255;
        return p;
    };
    unsigned long long* packed = (unsigned long long*)carve((size_t)n * 8);
    float* dinv        = (float*)carve((size_t)n * 4);
    int*   counts      = (int*)carve((size_t)n * 4);
    int*   row_start   = (int*)carve((size_t)(n + 1) * 4);
    int*   blockSums   = (int*)carve(128 * 4);
    int*   blockOffsets= (int*)carve(128 * 4);
    int*   rank        = (int*)carve((size_t)E * 4);
    int*   esrc        = (int*)carve((size_t)E * 4);
    float* ecoef       = (float*)carve((size_t)E * 4);
    unsigned short* w1t = (unsigned short*)carve((size_t)D * D * 2);
    unsigned short* w2t = (unsigned short*)carve((size_t)D * D * 2);
    unsigned short* xwb = (unsigned short*)carve((size_t)n * D * 2);
    unsigned short* hb  = (unsigned short*)carve((size_t)n * D * 2);

    const int nb_scan = (n + SCAN_B - 1) / SCAN_B;
    const int nb_edge = (E + 255) / 256;
    const int nb_node = (n + 255) / 256;

    hipMemsetAsync(packed, 0, (size_t)n * 8, stream);

    pass1_kernel<<<nb_edge, 256, 0, stream>>>(dst, ew, packed, rank, E);
    unpack_kernel<<<nb_node, 256, 0, stream>>>(packed, counts, dinv, n);
    scan1_kernel<<<nb_scan, SCAN_B, 0, stream>>>(counts, row_start, blockSums, n);
    scan2_kernel<<<1, 128, 0, stream>>>(blockSums, blockOffsets, nb_scan);
    scan3_kernel<<<nb_scan, SCAN_B, 0, stream>>>(row_start, blockOffsets, n, E);
    fill_kernel<<<nb_edge, 256, 0, stream>>>(src, dst, ew, rank, row_start, dinv, esrc, ecoef, E);

    cvt_wT_kernel<<<dim3(8, 8, 2), dim3(32, 32), 0, stream>>>(W1, W2, w1t, w2t);

    dim3 ggrid((n + GBM - 1) / GBM, D / GBN);
    dim3 agrid((n + 3) / 4);
    // layer 1 (A = x, fp32, converted during staging)
    gemm_bf16_kernel<true><<<ggrid, 256, 0, stream>>>(x, w1t, xwb, n);
    gather_kernel<true, true><<<agrid, 256, 0, stream>>>((const uint2*)xwb, row_start, esrc, ecoef,
                                                         dinv, b1, hb, n);
    // layer 2 (A = hb, bf16)
    gemm_bf16_kernel<false><<<ggrid, 256, 0, stream>>>(hb, w2t, xwb, n);
    gather_kernel<false, false><<<agrid, 256, 0, stream>>>((const uint2*)xwb, row_start, esrc, ecoef,
                                                           dinv, b2, out, n);
}